// Round 9
// baseline (639.015 us; speedup 1.0000x reference)
//
#include <hip/hip_runtime.h>

typedef __attribute__((ext_vector_type(4))) float fx4;
typedef __attribute__((ext_vector_type(8))) unsigned short u16x8;
typedef __attribute__((ext_vector_type(8))) __bf16 bf16x8;

static __device__ __forceinline__ unsigned short f2bf(float f) {
  unsigned int u = __builtin_bit_cast(unsigned int, f);
  u += 0x7fffu + ((u >> 16) & 1u);          // round-to-nearest-even
  return (unsigned short)(u >> 16);
}
static __device__ __forceinline__ fx4 mfma16(u16x8 a, u16x8 b, fx4 c) {
  return __builtin_amdgcn_mfma_f32_16x16x32_bf16(
      __builtin_bit_cast(bf16x8, a), __builtin_bit_cast(bf16x8, b), c, 0, 0, 0);
}

// XOR swizzles (16B-block granular). Weights are PRE-swizzled in ws by prep,
// so kernels copy them linearly into LDS and read with the same swizzle.
static __device__ __forceinline__ int swz128(int row, int col) {  // [.][128] bf16
  return row * 128 + (col ^ ((row & 7) << 3));
}
static __device__ __forceinline__ int swz32(int row, int col) {   // [.][32] bf16
  return row * 32 + (col ^ (((row >> 1) & 3) << 3));
}

// ---- ws layout (ushort units): weights bf16, [N][Kpad], pre-swizzled ----
#define WT_FE1 0        // [128][32]  (fe_W1, K=18 pad 32)
#define WT_FE2 4096     // [128][128] (fe_W2)
#define WT_EE1 20480    // [128][32]  (ee_W1, K=4 pad 32)
#define WT_EE2 24576    // [128][128] (ee_W2)
#define WT_A   40960    // [128][128] (ie_W1 rows 0..127   : sr_sum)
#define WT_B   57344    // [128][128] (ie_W1 rows 128..255 : node_sum)
#define WT_C   73728    // [128][128] (ie_W1 rows 256..383 : edge_latent)
#define WT_IE2 90112    // [128][128] (ie_W2)
#define WT_TOTAL 106496

__global__ void prep_weights(const float* __restrict__ feW1, const float* __restrict__ feW2,
                             const float* __restrict__ eeW1, const float* __restrict__ eeW2,
                             const float* __restrict__ ieW1, const float* __restrict__ ieW2,
                             unsigned short* __restrict__ wt) {
  int i = blockIdx.x * 256 + threadIdx.x;
  if (i >= WT_TOTAL) return;
  int base, n, k, kpad;
  float val;
  if (i < WT_FE2)      { base = WT_FE1; n = i >> 5; k = i & 31; kpad = 32;
                         val = (k < 18) ? feW1[k * 128 + n] : 0.f; }
  else if (i < WT_EE1) { base = WT_FE2; int j = i - WT_FE2; n = j >> 7; k = j & 127; kpad = 128;
                         val = feW2[k * 128 + n]; }
  else if (i < WT_EE2) { base = WT_EE1; int j = i - WT_EE1; n = j >> 5; k = j & 31; kpad = 32;
                         val = (k < 4) ? eeW1[k * 128 + n] : 0.f; }
  else if (i < WT_A)   { base = WT_EE2; int j = i - WT_EE2; n = j >> 7; k = j & 127; kpad = 128;
                         val = eeW2[k * 128 + n]; }
  else if (i < WT_B)   { base = WT_A;   int j = i - WT_A;   n = j >> 7; k = j & 127; kpad = 128;
                         val = ieW1[k * 128 + n]; }
  else if (i < WT_C)   { base = WT_B;   int j = i - WT_B;   n = j >> 7; k = j & 127; kpad = 128;
                         val = ieW1[(128 + k) * 128 + n]; }
  else if (i < WT_IE2) { base = WT_C;   int j = i - WT_C;   n = j >> 7; k = j & 127; kpad = 128;
                         val = ieW1[(256 + k) * 128 + n]; }
  else                 { base = WT_IE2; int j = i - WT_IE2; n = j >> 7; k = j & 127; kpad = 128;
                         val = ieW2[k * 128 + n]; }
  int dst = (kpad == 32) ? base + n * 32 + (k ^ (((n >> 1) & 3) << 3))
                         : base + n * 128 + (k ^ ((n & 7) << 3));
  wt[dst] = f2bf(val);
}

// 16-row GEMM, A from wave-local LDS arena, B from LDS (or global) weights,
// both swizzled.
template<int KPAD, int KT>
static __device__ __forceinline__ void gemm_lds(const unsigned short* As,
                                                const unsigned short* Ws,
                                                fx4* acc, int l16, int lgr) {
#pragma unroll
  for (int kk = 0; kk < KT; kk++) {
    const int k0 = kk * 32 + lgr * 8;
    u16x8 af = *(const u16x8*)(As + ((KPAD == 32) ? swz32(l16, k0) : swz128(l16, k0)));
#pragma unroll
    for (int nt = 0; nt < 8; nt++) {
      const int n = nt * 16 + l16;
      u16x8 bf = *(const u16x8*)(Ws + ((KPAD == 32) ? swz32(n, k0) : swz128(n, k0)));
      acc[nt] = mfma16(af, bf, acc[nt]);
    }
  }
}

// bias + ReLU -> bf16 store into wave-local [16][128] LDS slice.
static __device__ __forceinline__ void relu_store(fx4* acc, const float* __restrict__ bias,
                                                  unsigned short* dst, int l16, int lgr) {
#pragma unroll
  for (int nt = 0; nt < 8; nt++) {
    const int col = nt * 16 + l16;
    const float b = bias[col];
#pragma unroll
    for (int r = 0; r < 4; r++) {
      float v = acc[nt][r] + b;
      dst[swz128(lgr * 4 + r, col)] = f2bf(v > 0.f ? v : 0.f);
    }
  }
}

// bias add + per-row LayerNorm (normalize only; caller applies g/beta).
static __device__ __forceinline__ void ln_rows(fx4* acc, const float* __restrict__ bias, int l16) {
  float sum[4] = {0, 0, 0, 0}, sq[4] = {0, 0, 0, 0};
#pragma unroll
  for (int nt = 0; nt < 8; nt++) {
    const float b = bias[nt * 16 + l16];
#pragma unroll
    for (int r = 0; r < 4; r++) {
      float v = acc[nt][r] + b; acc[nt][r] = v;
      sum[r] += v; sq[r] += v * v;
    }
  }
#pragma unroll
  for (int r = 0; r < 4; r++) {
    float s_ = sum[r], q_ = sq[r];
#pragma unroll
    for (int m = 1; m < 16; m <<= 1) { s_ += __shfl_xor(s_, m, 64); q_ += __shfl_xor(q_, m, 64); }
    const float mu = s_ * (1.f / 128.f);
    const float rs = rsqrtf(q_ * (1.f / 128.f) - mu * mu + 1e-5f);
#pragma unroll
    for (int nt = 0; nt < 8; nt++) acc[nt][r] = (acc[nt][r] - mu) * rs;
  }
}

// ======================= fused fe+ee kernel =======================
// 1024 blocks x 512 threads, 80KB dyn LDS each -> exactly 2 blocks/CU (160KB),
// so fe-blocks and ee-blocks co-execute instead of serializing.
struct ParamsFE {
  const float* basis[3];
  const float* sv[6]; const float* rv[6];
  const float* b1; const float* b2; const float* g; const float* be;
};
struct ParamsEE {
  const float* dx; const float* attr;
  const float* b1; const float* b2; const float* g; const float* be;
};

static __device__ __forceinline__ void fe_body(const ParamsFE& p, unsigned short* lds,
                                               const unsigned short* wt, unsigned short* msg,
                                               int bid, int nblocks, int ntiles) {
  const int tid = threadIdx.x;
  const int wave = tid >> 6, lane = tid & 63;
  const int l16 = lane & 15, lgr = lane >> 4;
#pragma unroll
  for (int i = tid * 8; i < 20480; i += 4096)
    *(u16x8*)(lds + i) = *(const u16x8*)(wt + WT_FE1 + i);
  const unsigned short* W1 = lds;
  const unsigned short* W2 = lds + 4096;
  unsigned short* h1 = lds + 20480 + wave * 2560;
  unsigned short* feat = h1 + 2048;
  __syncthreads();
  // persistent zeros in feat cols 18..31 (never overwritten)
#pragma unroll
  for (int j = 0; j < 4; j++) { int c = 18 + lgr * 4 + j; if (c < 32) feat[swz32(l16, c)] = 0; }
  const fx4 z4 = {0.f, 0.f, 0.f, 0.f};

  for (int t = bid; t < ntiles; t += nblocks) {
    const int e0 = t * 128 + wave * 16;
    const size_t e = (size_t)(e0 + l16);
    float bx[3][3];
#pragma unroll
    for (int i = 0; i < 3; i++) {
      const float* bp = p.basis[i] + 3 * e;
      bx[i][0] = bp[0]; bx[i][1] = bp[1]; bx[i][2] = bp[2];
    }
    fx4 latS[8];
#pragma unroll
    for (int side = 0; side < 2; side++) {
      const bool isR = (side == 1);
#pragma unroll
      for (int k = 0; k < 6; k++) {
        if ((k & 3) == lgr) {   // compile-time k; exec-masked lanes
          const float* vp = (isR ? p.rv[k] : p.sv[k]) + 3 * e;
          const float v0 = vp[0], v1 = vp[1], v2 = vp[2];
          const float sgn = (isR && k != 3 && k != 5) ? -1.f : 1.f;
#pragma unroll
          for (int i = 0; i < 3; i++) {
            float d = (bx[i][0] * v0 + bx[i][1] * v1 + bx[i][2] * v2) * sgn;
            feat[swz32(l16, k * 3 + i)] = f2bf(d);
          }
        }
      }
      fx4 acc[8];
#pragma unroll
      for (int b = 0; b < 8; b++) acc[b] = z4;
      gemm_lds<32, 1>(feat, W1, acc, l16, lgr);
      relu_store(acc, p.b1, h1, l16, lgr);
#pragma unroll
      for (int b = 0; b < 8; b++) acc[b] = z4;
      gemm_lds<128, 4>(h1, W2, acc, l16, lgr);
      ln_rows(acc, p.b2, l16);
      if (!isR) {
#pragma unroll
        for (int nt = 0; nt < 8; nt++) {
          const int col = nt * 16 + l16;
          const float gg = p.g[col], bb = p.be[col];
#pragma unroll
          for (int r = 0; r < 4; r++) latS[nt][r] = acc[nt][r] * gg + bb;
        }
      } else {
#pragma unroll
        for (int nt = 0; nt < 8; nt++) {
          const int col = nt * 16 + l16;
          const float gg = p.g[col], bb = p.be[col];
#pragma unroll
          for (int r = 0; r < 4; r++)
            msg[(size_t)(e0 + lgr * 4 + r) * 256 + col] =
                f2bf(latS[nt][r] + acc[nt][r] * gg + bb);
        }
      }
    }
  }
}

static __device__ __forceinline__ void ee_body(const ParamsEE& p, unsigned short* lds,
                                               const unsigned short* wt, unsigned short* msg,
                                               int bid, int nblocks, int ntiles) {
  const int tid = threadIdx.x;
  const int wave = tid >> 6, lane = tid & 63;
  const int l16 = lane & 15, lgr = lane >> 4;
#pragma unroll
  for (int i = tid * 8; i < 20480; i += 4096)
    *(u16x8*)(lds + i) = *(const u16x8*)(wt + WT_EE1 + i);
  const unsigned short* W1 = lds;
  const unsigned short* W2 = lds + 4096;
  unsigned short* h1 = lds + 20480 + wave * 2560;
  unsigned short* feat = h1 + 2048;
  __syncthreads();
  // persistent zeros cols 4..31
#pragma unroll
  for (int j = 0; j < 7; j++) feat[swz32(l16, 4 + lgr * 7 + j)] = 0;
  const fx4 z4 = {0.f, 0.f, 0.f, 0.f};

  for (int t = bid; t < ntiles; t += nblocks) {
    const int e0 = t * 128 + wave * 16;
    const size_t e = (size_t)(e0 + l16);
    if (lgr == 0) {
      float d0 = p.dx[3 * e], d1 = p.dx[3 * e + 1], d2 = p.dx[3 * e + 2];
      feat[swz32(l16, 0)] = f2bf(sqrtf(d0 * d0 + d1 * d1 + d2 * d2));
    } else {
      feat[swz32(l16, lgr)] = f2bf(p.attr[3 * e + (lgr - 1)]);
    }
    fx4 acc[8];
#pragma unroll
    for (int b = 0; b < 8; b++) acc[b] = z4;
    gemm_lds<32, 1>(feat, W1, acc, l16, lgr);
    relu_store(acc, p.b1, h1, l16, lgr);
#pragma unroll
    for (int b = 0; b < 8; b++) acc[b] = z4;
    gemm_lds<128, 4>(h1, W2, acc, l16, lgr);
    ln_rows(acc, p.b2, l16);
#pragma unroll
    for (int nt = 0; nt < 8; nt++) {
      const int col = nt * 16 + l16;
      const float gg = p.g[col], bb = p.be[col];
#pragma unroll
      for (int r = 0; r < 4; r++)
        msg[(size_t)(e0 + lgr * 4 + r) * 256 + 128 + col] =
            f2bf(acc[nt][r] * gg + bb);
    }
  }
}

__global__ __launch_bounds__(512) void feee_kernel(ParamsFE pf, ParamsEE pe,
                                                   const unsigned short* wt,
                                                   unsigned short* msg,
                                                   int nfe, int ntiles) {
  extern __shared__ unsigned short lds[];  // 40960 ushorts (80KB)
  if ((int)blockIdx.x < nfe)
    fe_body(pf, lds, wt, msg, blockIdx.x, nfe, ntiles);
  else
    ee_body(pe, lds, wt, msg, blockIdx.x - nfe, gridDim.x - nfe, ntiles);
}

// ============ ie kernel (fused layer1 + layer2 + LN -> out f32) ============
// 768 threads = 12 waves = 3 waves/SIMD. CRITICAL: plain __launch_bounds__(N)
// budgets VGPRs for 2 workgroups/CU (512thr->128, 768->84, 1024->64, measured
// R6-R8); at 768 that spills the MFMA accumulators. The explicit min-waves
// arg (768,3) sets budget 512/3=170 >= the ~130 this kernel needs. The
// (256,3) failure in R2/R3 was budget(170) < need(196) - budget>=need is the
// rule, not "never use min-waves".
// Dyn LDS 144KB: WA|WB|WC 96KB + 12 x 4KB per-wave h1 arenas. 1 block/CU.
// W2 (32KB) is read from GLOBAL per-fragment: it fits L1 entirely.
struct ParamsIE {
  const int* eidx;
  const float* nl;
  const float* b1; const float* b2; const float* g; const float* be;
  const unsigned short* wt;
  const unsigned short* msg;  // aliases out (rows consumed before overwrite)
  float* out;
  int E; int nt16;            // nt16 = E/16 tiles
};

__global__ __launch_bounds__(768, 3) void ie_kernel(ParamsIE p) {
  extern __shared__ unsigned short dyn[];  // 49152 weights + 12*2048 arenas
  const int tid = threadIdx.x;
  const int wave = tid >> 6, lane = tid & 63;
  const int l16 = lane & 15, lgr = lane >> 4;
  for (int i = tid * 8; i < 49152; i += 6144)
    *(u16x8*)(dyn + i) = *(const u16x8*)(p.wt + WT_A + i);
  const unsigned short* WA = dyn;
  const unsigned short* WB = dyn + 16384;
  const unsigned short* WC = dyn + 32768;
  unsigned short* h1 = dyn + 49152 + wave * 2048;
  __syncthreads();
  const fx4 z4 = {0.f, 0.f, 0.f, 0.f};

  const int gw = blockIdx.x * 12 + wave;       // global wave id
  const int gstride = gridDim.x * 12;
  for (int t = gw; t < p.nt16; t += gstride) {
    const int e0 = t * 16;
    const size_t e = (size_t)(e0 + l16);
    const int sidx = p.eidx[e];
    const int ridx = p.eidx[(size_t)p.E + e];
    const unsigned short* mrow = p.msg + e * 256;
    const float* ns = p.nl + (size_t)sidx * 128;
    const float* nr = p.nl + (size_t)ridx * 128;
    fx4 acc[8];
#pragma unroll
    for (int b = 0; b < 8; b++) acc[b] = z4;
    // node chunks first (longest-latency gathers issue early)
#pragma unroll
    for (int c = 0; c < 4; c++) {
      const int k0 = c * 32 + lgr * 8;
      fx4 a0 = *(const fx4*)(ns + k0), a1 = *(const fx4*)(ns + k0 + 4);
      fx4 b0 = *(const fx4*)(nr + k0), b1 = *(const fx4*)(nr + k0 + 4);
      u16x8 af;
#pragma unroll
      for (int j = 0; j < 4; j++) { af[j] = f2bf(a0[j] + b0[j]); af[4 + j] = f2bf(a1[j] + b1[j]); }
#pragma unroll
      for (int nt = 0; nt < 8; nt++) {
        u16x8 bf = *(const u16x8*)(WB + swz128(nt * 16 + l16, k0));
        acc[nt] = mfma16(af, bf, acc[nt]);
      }
    }
    // sr chunks (msg cols 0..127, linear layout)
#pragma unroll
    for (int c = 0; c < 4; c++) {
      const int k0 = c * 32 + lgr * 8;
      u16x8 af = *(const u16x8*)(mrow + k0);
#pragma unroll
      for (int nt = 0; nt < 8; nt++) {
        u16x8 bf = *(const u16x8*)(WA + swz128(nt * 16 + l16, k0));
        acc[nt] = mfma16(af, bf, acc[nt]);
      }
    }
    // el chunks (msg cols 128..255)
#pragma unroll
    for (int c = 0; c < 4; c++) {
      const int k0 = c * 32 + lgr * 8;
      u16x8 af = *(const u16x8*)(mrow + 128 + k0);
#pragma unroll
      for (int nt = 0; nt < 8; nt++) {
        u16x8 bf = *(const u16x8*)(WC + swz128(nt * 16 + l16, k0));
        acc[nt] = mfma16(af, bf, acc[nt]);
      }
    }
    // ReLU -> per-wave LDS arena
    relu_store(acc, p.b1, h1, l16, lgr);
    // layer 2: A from arena (LDS), B from global W2 (L1-resident 32KB)
#pragma unroll
    for (int b = 0; b < 8; b++) acc[b] = z4;
    gemm_lds<128, 4>(h1, p.wt + WT_IE2, acc, l16, lgr);
    ln_rows(acc, p.b2, l16);
#pragma unroll
    for (int nt = 0; nt < 8; nt++) {
      const int col = nt * 16 + l16;
      const float gg = p.g[col], bb = p.be[col];
#pragma unroll
      for (int r = 0; r < 4; r++)
        p.out[(size_t)(e0 + lgr * 4 + r) * 128 + col] = acc[nt][r] * gg + bb;
    }
  }
}

extern "C" void kernel_launch(void* const* d_in, const int* in_sizes, int n_in,
                              void* d_out, int out_size, void* d_ws, size_t ws_size,
                              hipStream_t stream) {
  (void)n_in; (void)out_size;
  const int E = in_sizes[1] / 3;  // edge_dx_ is [E,3]
  unsigned short* wt = reinterpret_cast<unsigned short*>(d_ws);
  if (ws_size < (size_t)WT_TOTAL * sizeof(unsigned short)) return;

  prep_weights<<<(WT_TOTAL + 255) / 256, 256, 0, stream>>>(
      (const float*)d_in[19], (const float*)d_in[21],
      (const float*)d_in[25], (const float*)d_in[27],
      (const float*)d_in[31], (const float*)d_in[33], wt);

  unsigned short* msg = (unsigned short*)d_out;  // [E][256] bf16 staging inside d_out

  hipFuncSetAttribute((const void*)feee_kernel,
                      hipFuncAttributeMaxDynamicSharedMemorySize, 81920);
  hipFuncSetAttribute((const void*)ie_kernel,
                      hipFuncAttributeMaxDynamicSharedMemorySize, 147456);

  ParamsFE pf;
  for (int i = 0; i < 3; i++) pf.basis[i] = (const float*)d_in[3 + i];
  for (int k = 0; k < 6; k++) { pf.sv[k] = (const float*)d_in[6 + k]; pf.rv[k] = (const float*)d_in[12 + k]; }
  pf.b1 = (const float*)d_in[20]; pf.b2 = (const float*)d_in[22];
  pf.g  = (const float*)d_in[23]; pf.be = (const float*)d_in[24];

  ParamsEE pe;
  pe.dx = (const float*)d_in[1]; pe.attr = (const float*)d_in[2];
  pe.b1 = (const float*)d_in[26]; pe.b2 = (const float*)d_in[28];
  pe.g  = (const float*)d_in[29]; pe.be = (const float*)d_in[30];

  feee_kernel<<<1024, 512, 81920, stream>>>(pf, pe, wt, msg, 512, E / 128);

  ParamsIE pi;
  pi.eidx = (const int*)d_in[0];
  pi.nl = (const float*)d_in[18];
  pi.b1 = (const float*)d_in[32]; pi.b2 = (const float*)d_in[34];
  pi.g  = (const float*)d_in[35]; pi.be = (const float*)d_in[36];
  pi.wt = wt; pi.msg = msg; pi.out = (float*)d_out;
  pi.E = E; pi.nt16 = E / 16;
  ie_kernel<<<256, 768, 147456, stream>>>(pi);
}

// Round 10
// 624.208 us; speedup vs baseline: 1.0237x; 1.0237x over previous
//
#include <hip/hip_runtime.h>

typedef __attribute__((ext_vector_type(4))) float fx4;
typedef __attribute__((ext_vector_type(8))) unsigned short u16x8;
typedef __attribute__((ext_vector_type(8))) __bf16 bf16x8;

static __device__ __forceinline__ unsigned short f2bf(float f) {
  unsigned int u = __builtin_bit_cast(unsigned int, f);
  u += 0x7fffu + ((u >> 16) & 1u);          // round-to-nearest-even
  return (unsigned short)(u >> 16);
}
static __device__ __forceinline__ fx4 mfma16(u16x8 a, u16x8 b, fx4 c) {
  return __builtin_amdgcn_mfma_f32_16x16x32_bf16(
      __builtin_bit_cast(bf16x8, a), __builtin_bit_cast(bf16x8, b), c, 0, 0, 0);
}

// XOR swizzles (16B-block granular). Weights are PRE-swizzled in ws by prep,
// so kernels copy them linearly into LDS and read with the same swizzle.
static __device__ __forceinline__ int swz128(int row, int col) {  // [.][128] bf16
  return row * 128 + (col ^ ((row & 7) << 3));
}
static __device__ __forceinline__ int swz32(int row, int col) {   // [.][32] bf16
  return row * 32 + (col ^ (((row >> 1) & 3) << 3));
}

// ---- ws layout (ushort units): weights bf16, [N][Kpad], pre-swizzled ----
#define WT_FE1 0        // [128][32]  (fe_W1, K=18 pad 32)
#define WT_FE2 4096     // [128][128] (fe_W2)
#define WT_EE1 20480    // [128][32]  (ee_W1, K=4 pad 32)
#define WT_EE2 24576    // [128][128] (ee_W2)
#define WT_A   40960    // [128][128] (ie_W1 rows 0..127   : sr_sum)
#define WT_B   57344    // [128][128] (ie_W1 rows 128..255 : node_sum)
#define WT_C   73728    // [128][128] (ie_W1 rows 256..383 : edge_latent)
#define WT_IE2 90112    // [128][128] (ie_W2)
#define WT_TOTAL 106496

__global__ void prep_weights(const float* __restrict__ feW1, const float* __restrict__ feW2,
                             const float* __restrict__ eeW1, const float* __restrict__ eeW2,
                             const float* __restrict__ ieW1, const float* __restrict__ ieW2,
                             unsigned short* __restrict__ wt) {
  int i = blockIdx.x * 256 + threadIdx.x;
  if (i >= WT_TOTAL) return;
  int base, n, k, kpad;
  float val;
  if (i < WT_FE2)      { base = WT_FE1; n = i >> 5; k = i & 31; kpad = 32;
                         val = (k < 18) ? feW1[k * 128 + n] : 0.f; }
  else if (i < WT_EE1) { base = WT_FE2; int j = i - WT_FE2; n = j >> 7; k = j & 127; kpad = 128;
                         val = feW2[k * 128 + n]; }
  else if (i < WT_EE2) { base = WT_EE1; int j = i - WT_EE1; n = j >> 5; k = j & 31; kpad = 32;
                         val = (k < 4) ? eeW1[k * 128 + n] : 0.f; }
  else if (i < WT_A)   { base = WT_EE2; int j = i - WT_EE2; n = j >> 7; k = j & 127; kpad = 128;
                         val = eeW2[k * 128 + n]; }
  else if (i < WT_B)   { base = WT_A;   int j = i - WT_A;   n = j >> 7; k = j & 127; kpad = 128;
                         val = ieW1[k * 128 + n]; }
  else if (i < WT_C)   { base = WT_B;   int j = i - WT_B;   n = j >> 7; k = j & 127; kpad = 128;
                         val = ieW1[(128 + k) * 128 + n]; }
  else if (i < WT_IE2) { base = WT_C;   int j = i - WT_C;   n = j >> 7; k = j & 127; kpad = 128;
                         val = ieW1[(256 + k) * 128 + n]; }
  else                 { base = WT_IE2; int j = i - WT_IE2; n = j >> 7; k = j & 127; kpad = 128;
                         val = ieW2[k * 128 + n]; }
  int dst = (kpad == 32) ? base + n * 32 + (k ^ (((n >> 1) & 3) << 3))
                         : base + n * 128 + (k ^ ((n & 7) << 3));
  wt[dst] = f2bf(val);
}

// 16-row GEMM, A from wave-local LDS arena, B from LDS (or global) weights,
// both swizzled.
template<int KPAD, int KT>
static __device__ __forceinline__ void gemm_lds(const unsigned short* As,
                                                const unsigned short* Ws,
                                                fx4* acc, int l16, int lgr) {
#pragma unroll
  for (int kk = 0; kk < KT; kk++) {
    const int k0 = kk * 32 + lgr * 8;
    u16x8 af = *(const u16x8*)(As + ((KPAD == 32) ? swz32(l16, k0) : swz128(l16, k0)));
#pragma unroll
    for (int nt = 0; nt < 8; nt++) {
      const int n = nt * 16 + l16;
      u16x8 bf = *(const u16x8*)(Ws + ((KPAD == 32) ? swz32(n, k0) : swz128(n, k0)));
      acc[nt] = mfma16(af, bf, acc[nt]);
    }
  }
}

// bias + ReLU -> bf16 store into wave-local [16][128] LDS slice.
static __device__ __forceinline__ void relu_store(fx4* acc, const float* __restrict__ bias,
                                                  unsigned short* dst, int l16, int lgr) {
#pragma unroll
  for (int nt = 0; nt < 8; nt++) {
    const int col = nt * 16 + l16;
    const float b = bias[col];
#pragma unroll
    for (int r = 0; r < 4; r++) {
      float v = acc[nt][r] + b;
      dst[swz128(lgr * 4 + r, col)] = f2bf(v > 0.f ? v : 0.f);
    }
  }
}

// bias add + per-row LayerNorm (normalize only; caller applies g/beta).
static __device__ __forceinline__ void ln_rows(fx4* acc, const float* __restrict__ bias, int l16) {
  float sum[4] = {0, 0, 0, 0}, sq[4] = {0, 0, 0, 0};
#pragma unroll
  for (int nt = 0; nt < 8; nt++) {
    const float b = bias[nt * 16 + l16];
#pragma unroll
    for (int r = 0; r < 4; r++) {
      float v = acc[nt][r] + b; acc[nt][r] = v;
      sum[r] += v; sq[r] += v * v;
    }
  }
#pragma unroll
  for (int r = 0; r < 4; r++) {
    float s_ = sum[r], q_ = sq[r];
#pragma unroll
    for (int m = 1; m < 16; m <<= 1) { s_ += __shfl_xor(s_, m, 64); q_ += __shfl_xor(q_, m, 64); }
    const float mu = s_ * (1.f / 128.f);
    const float rs = rsqrtf(q_ * (1.f / 128.f) - mu * mu + 1e-5f);
#pragma unroll
    for (int nt = 0; nt < 8; nt++) acc[nt][r] = (acc[nt][r] - mu) * rs;
  }
}

// ======================= fused fe+ee kernel =======================
// 1024 blocks x 512 threads, 80KB dyn LDS each -> exactly 2 blocks/CU (160KB),
// so fe-blocks and ee-blocks co-execute instead of serializing.
struct ParamsFE {
  const float* basis[3];
  const float* sv[6]; const float* rv[6];
  const float* b1; const float* b2; const float* g; const float* be;
};
struct ParamsEE {
  const float* dx; const float* attr;
  const float* b1; const float* b2; const float* g; const float* be;
};

static __device__ __forceinline__ void fe_body(const ParamsFE& p, unsigned short* lds,
                                               const unsigned short* wt, unsigned short* msg,
                                               int bid, int nblocks, int ntiles) {
  const int tid = threadIdx.x;
  const int wave = tid >> 6, lane = tid & 63;
  const int l16 = lane & 15, lgr = lane >> 4;
#pragma unroll
  for (int i = tid * 8; i < 20480; i += 4096)
    *(u16x8*)(lds + i) = *(const u16x8*)(wt + WT_FE1 + i);
  const unsigned short* W1 = lds;
  const unsigned short* W2 = lds + 4096;
  unsigned short* h1 = lds + 20480 + wave * 2560;
  unsigned short* feat = h1 + 2048;
  __syncthreads();
  // persistent zeros in feat cols 18..31 (never overwritten)
#pragma unroll
  for (int j = 0; j < 4; j++) { int c = 18 + lgr * 4 + j; if (c < 32) feat[swz32(l16, c)] = 0; }
  const fx4 z4 = {0.f, 0.f, 0.f, 0.f};

  for (int t = bid; t < ntiles; t += nblocks) {
    const int e0 = t * 128 + wave * 16;
    const size_t e = (size_t)(e0 + l16);
    float bx[3][3];
#pragma unroll
    for (int i = 0; i < 3; i++) {
      const float* bp = p.basis[i] + 3 * e;
      bx[i][0] = bp[0]; bx[i][1] = bp[1]; bx[i][2] = bp[2];
    }
    fx4 latS[8];
#pragma unroll
    for (int side = 0; side < 2; side++) {
      const bool isR = (side == 1);
#pragma unroll
      for (int k = 0; k < 6; k++) {
        if ((k & 3) == lgr) {   // compile-time k; exec-masked lanes
          const float* vp = (isR ? p.rv[k] : p.sv[k]) + 3 * e;
          const float v0 = vp[0], v1 = vp[1], v2 = vp[2];
          const float sgn = (isR && k != 3 && k != 5) ? -1.f : 1.f;
#pragma unroll
          for (int i = 0; i < 3; i++) {
            float d = (bx[i][0] * v0 + bx[i][1] * v1 + bx[i][2] * v2) * sgn;
            feat[swz32(l16, k * 3 + i)] = f2bf(d);
          }
        }
      }
      fx4 acc[8];
#pragma unroll
      for (int b = 0; b < 8; b++) acc[b] = z4;
      gemm_lds<32, 1>(feat, W1, acc, l16, lgr);
      relu_store(acc, p.b1, h1, l16, lgr);
#pragma unroll
      for (int b = 0; b < 8; b++) acc[b] = z4;
      gemm_lds<128, 4>(h1, W2, acc, l16, lgr);
      ln_rows(acc, p.b2, l16);
      if (!isR) {
#pragma unroll
        for (int nt = 0; nt < 8; nt++) {
          const int col = nt * 16 + l16;
          const float gg = p.g[col], bb = p.be[col];
#pragma unroll
          for (int r = 0; r < 4; r++) latS[nt][r] = acc[nt][r] * gg + bb;
        }
      } else {
#pragma unroll
        for (int nt = 0; nt < 8; nt++) {
          const int col = nt * 16 + l16;
          const float gg = p.g[col], bb = p.be[col];
#pragma unroll
          for (int r = 0; r < 4; r++)
            msg[(size_t)(e0 + lgr * 4 + r) * 256 + col] =
                f2bf(latS[nt][r] + acc[nt][r] * gg + bb);
        }
      }
    }
  }
}

static __device__ __forceinline__ void ee_body(const ParamsEE& p, unsigned short* lds,
                                               const unsigned short* wt, unsigned short* msg,
                                               int bid, int nblocks, int ntiles) {
  const int tid = threadIdx.x;
  const int wave = tid >> 6, lane = tid & 63;
  const int l16 = lane & 15, lgr = lane >> 4;
#pragma unroll
  for (int i = tid * 8; i < 20480; i += 4096)
    *(u16x8*)(lds + i) = *(const u16x8*)(wt + WT_EE1 + i);
  const unsigned short* W1 = lds;
  const unsigned short* W2 = lds + 4096;
  unsigned short* h1 = lds + 20480 + wave * 2560;
  unsigned short* feat = h1 + 2048;
  __syncthreads();
  // persistent zeros cols 4..31
#pragma unroll
  for (int j = 0; j < 7; j++) feat[swz32(l16, 4 + lgr * 7 + j)] = 0;
  const fx4 z4 = {0.f, 0.f, 0.f, 0.f};

  for (int t = bid; t < ntiles; t += nblocks) {
    const int e0 = t * 128 + wave * 16;
    const size_t e = (size_t)(e0 + l16);
    if (lgr == 0) {
      float d0 = p.dx[3 * e], d1 = p.dx[3 * e + 1], d2 = p.dx[3 * e + 2];
      feat[swz32(l16, 0)] = f2bf(sqrtf(d0 * d0 + d1 * d1 + d2 * d2));
    } else {
      feat[swz32(l16, lgr)] = f2bf(p.attr[3 * e + (lgr - 1)]);
    }
    fx4 acc[8];
#pragma unroll
    for (int b = 0; b < 8; b++) acc[b] = z4;
    gemm_lds<32, 1>(feat, W1, acc, l16, lgr);
    relu_store(acc, p.b1, h1, l16, lgr);
#pragma unroll
    for (int b = 0; b < 8; b++) acc[b] = z4;
    gemm_lds<128, 4>(h1, W2, acc, l16, lgr);
    ln_rows(acc, p.b2, l16);
#pragma unroll
    for (int nt = 0; nt < 8; nt++) {
      const int col = nt * 16 + l16;
      const float gg = p.g[col], bb = p.be[col];
#pragma unroll
      for (int r = 0; r < 4; r++)
        msg[(size_t)(e0 + lgr * 4 + r) * 256 + 128 + col] =
            f2bf(acc[nt][r] * gg + bb);
    }
  }
}

__global__ __launch_bounds__(512) void feee_kernel(ParamsFE pf, ParamsEE pe,
                                                   const unsigned short* wt,
                                                   unsigned short* msg,
                                                   int nfe, int ntiles) {
  extern __shared__ unsigned short lds[];  // 40960 ushorts (80KB)
  if ((int)blockIdx.x < nfe)
    fe_body(pf, lds, wt, msg, blockIdx.x, nfe, ntiles);
  else
    ee_body(pe, lds, wt, msg, blockIdx.x - nfe, gridDim.x - nfe, ntiles);
}

// ============ ie kernel (fused layer1 + layer2 + LN -> out f32) ============
// 512 threads = 8 waves. M=32 per wave: two 16-row sub-tiles (A/B) share every
// B-fragment -> B reads per MFMA halve; two independent acc chains double MLP.
// VGPR-budget model (measured R4-R9): plain __launch_bounds__(N) -> budget
// 512/(2*wavesPerBlock) (256->196ok, 512->128, 768->84, 1024->64);
// (_,min) -> budget 256/min. So (512,1) -> 256, enough for the ~180 this
// kernel needs. If VGPR comes back 84 / FETCH >500MB, the model is wrong ->
// revert to R7's M=16 at plain (512).
// Dyn LDS 128KB: WA|WC 64KB + 8 x 8KB per-wave h1 arenas. WB and W2 are read
// from GLOBAL per-fragment (32KB each, L1-resident, phase-separated).
struct ParamsIE {
  const int* eidx;
  const float* nl;
  const float* b1; const float* b2; const float* g; const float* be;
  const unsigned short* wt;
  const unsigned short* msg;  // aliases out (rows consumed before overwrite)
  float* out;
  int E; int nt32;            // nt32 = E/32 tiles
};

__global__ __launch_bounds__(512, 1) void ie_kernel(ParamsIE p) {
  extern __shared__ unsigned short dyn[];  // WA 16384 | WC 16384 | 8 x 4096 arenas
  const int tid = threadIdx.x;
  const int wave = tid >> 6, lane = tid & 63;
  const int l16 = lane & 15, lgr = lane >> 4;
#pragma unroll
  for (int i = tid * 8; i < 16384; i += 4096) {
    *(u16x8*)(dyn + i) = *(const u16x8*)(p.wt + WT_A + i);
    *(u16x8*)(dyn + 16384 + i) = *(const u16x8*)(p.wt + WT_C + i);
  }
  const unsigned short* WA = dyn;
  const unsigned short* WC = dyn + 16384;
  unsigned short* h1 = dyn + 32768 + wave * 4096;   // [32][128] bf16, swizzled
  __syncthreads();
  const fx4 z4 = {0.f, 0.f, 0.f, 0.f};

  const int gw = blockIdx.x * 8 + wave;        // global wave id
  const int gstride = gridDim.x * 8;
  for (int t = gw; t < p.nt32; t += gstride) {
    const int e0 = t * 32;
    const size_t eA = (size_t)(e0 + l16);
    const size_t eB = (size_t)(e0 + 16 + l16);
    const int sA = p.eidx[eA], rA = p.eidx[(size_t)p.E + eA];
    const int sB = p.eidx[eB], rB = p.eidx[(size_t)p.E + eB];
    const unsigned short* mrowA = p.msg + eA * 256;
    const unsigned short* mrowB = p.msg + eB * 256;
    const float* nsA = p.nl + (size_t)sA * 128;
    const float* nrA = p.nl + (size_t)rA * 128;
    const float* nsB = p.nl + (size_t)sB * 128;
    const float* nrB = p.nl + (size_t)rB * 128;
    fx4 accA[8], accB[8];
#pragma unroll
    for (int b = 0; b < 8; b++) { accA[b] = z4; accB[b] = z4; }
    // ---- node GEMM (B = WB from GLOBAL, L1-resident) ----
#pragma unroll
    for (int c = 0; c < 4; c++) {
      const int k0 = c * 32 + lgr * 8;
      fx4 a0 = *(const fx4*)(nsA + k0), a1 = *(const fx4*)(nsA + k0 + 4);
      fx4 b0 = *(const fx4*)(nrA + k0), b1 = *(const fx4*)(nrA + k0 + 4);
      fx4 c0 = *(const fx4*)(nsB + k0), c1 = *(const fx4*)(nsB + k0 + 4);
      fx4 d0 = *(const fx4*)(nrB + k0), d1 = *(const fx4*)(nrB + k0 + 4);
      u16x8 afA, afB;
#pragma unroll
      for (int j = 0; j < 4; j++) {
        afA[j] = f2bf(a0[j] + b0[j]); afA[4 + j] = f2bf(a1[j] + b1[j]);
        afB[j] = f2bf(c0[j] + d0[j]); afB[4 + j] = f2bf(c1[j] + d1[j]);
      }
#pragma unroll
      for (int nt = 0; nt < 8; nt++) {
        u16x8 bf = *(const u16x8*)(p.wt + WT_B + swz128(nt * 16 + l16, k0));
        accA[nt] = mfma16(afA, bf, accA[nt]);
        accB[nt] = mfma16(afB, bf, accB[nt]);
      }
    }
    // ---- sr GEMM (B = WA from LDS) ----
#pragma unroll
    for (int c = 0; c < 4; c++) {
      const int k0 = c * 32 + lgr * 8;
      u16x8 afA = *(const u16x8*)(mrowA + k0);
      u16x8 afB = *(const u16x8*)(mrowB + k0);
#pragma unroll
      for (int nt = 0; nt < 8; nt++) {
        u16x8 bf = *(const u16x8*)(WA + swz128(nt * 16 + l16, k0));
        accA[nt] = mfma16(afA, bf, accA[nt]);
        accB[nt] = mfma16(afB, bf, accB[nt]);
      }
    }
    // ---- el GEMM (B = WC from LDS) ----
#pragma unroll
    for (int c = 0; c < 4; c++) {
      const int k0 = c * 32 + lgr * 8;
      u16x8 afA = *(const u16x8*)(mrowA + 128 + k0);
      u16x8 afB = *(const u16x8*)(mrowB + 128 + k0);
#pragma unroll
      for (int nt = 0; nt < 8; nt++) {
        u16x8 bf = *(const u16x8*)(WC + swz128(nt * 16 + l16, k0));
        accA[nt] = mfma16(afA, bf, accA[nt]);
        accB[nt] = mfma16(afB, bf, accB[nt]);
      }
    }
    // ---- ReLU -> per-wave LDS arena (two 16-row halves) ----
    relu_store(accA, p.b1, h1, l16, lgr);
    relu_store(accB, p.b1, h1 + 2048, l16, lgr);
    // ---- layer 2: A from arena, B = W2 from GLOBAL (L1-resident) ----
#pragma unroll
    for (int b = 0; b < 8; b++) { accA[b] = z4; accB[b] = z4; }
#pragma unroll
    for (int c = 0; c < 4; c++) {
      const int k0 = c * 32 + lgr * 8;
      u16x8 afA = *(const u16x8*)(h1 + swz128(l16, k0));
      u16x8 afB = *(const u16x8*)(h1 + 2048 + swz128(l16, k0));
#pragma unroll
      for (int nt = 0; nt < 8; nt++) {
        u16x8 bf = *(const u16x8*)(p.wt + WT_IE2 + swz128(nt * 16 + l16, k0));
        accA[nt] = mfma16(afA, bf, accA[nt]);
        accB[nt] = mfma16(afB, bf, accB[nt]);
      }
    }
    ln_rows(accA, p.b2, l16);
    ln_rows(accB, p.b2, l16);
#pragma unroll
    for (int nt = 0; nt < 8; nt++) {
      const int col = nt * 16 + l16;
      const float gg = p.g[col], bb = p.be[col];
#pragma unroll
      for (int r = 0; r < 4; r++) {
        p.out[(size_t)(e0 + lgr * 4 + r) * 128 + col] = accA[nt][r] * gg + bb;
        p.out[(size_t)(e0 + 16 + lgr * 4 + r) * 128 + col] = accB[nt][r] * gg + bb;
      }
    }
  }
}

extern "C" void kernel_launch(void* const* d_in, const int* in_sizes, int n_in,
                              void* d_out, int out_size, void* d_ws, size_t ws_size,
                              hipStream_t stream) {
  (void)n_in; (void)out_size;
  const int E = in_sizes[1] / 3;  // edge_dx_ is [E,3]
  unsigned short* wt = reinterpret_cast<unsigned short*>(d_ws);
  if (ws_size < (size_t)WT_TOTAL * sizeof(unsigned short)) return;

  prep_weights<<<(WT_TOTAL + 255) / 256, 256, 0, stream>>>(
      (const float*)d_in[19], (const float*)d_in[21],
      (const float*)d_in[25], (const float*)d_in[27],
      (const float*)d_in[31], (const float*)d_in[33], wt);

  unsigned short* msg = (unsigned short*)d_out;  // [E][256] bf16 staging inside d_out

  hipFuncSetAttribute((const void*)feee_kernel,
                      hipFuncAttributeMaxDynamicSharedMemorySize, 81920);
  hipFuncSetAttribute((const void*)ie_kernel,
                      hipFuncAttributeMaxDynamicSharedMemorySize, 131072);

  ParamsFE pf;
  for (int i = 0; i < 3; i++) pf.basis[i] = (const float*)d_in[3 + i];
  for (int k = 0; k < 6; k++) { pf.sv[k] = (const float*)d_in[6 + k]; pf.rv[k] = (const float*)d_in[12 + k]; }
  pf.b1 = (const float*)d_in[20]; pf.b2 = (const float*)d_in[22];
  pf.g  = (const float*)d_in[23]; pf.be = (const float*)d_in[24];

  ParamsEE pe;
  pe.dx = (const float*)d_in[1]; pe.attr = (const float*)d_in[2];
  pe.b1 = (const float*)d_in[26]; pe.b2 = (const float*)d_in[28];
  pe.g  = (const float*)d_in[29]; pe.be = (const float*)d_in[30];

  feee_kernel<<<1024, 512, 81920, stream>>>(pf, pe, wt, msg, 512, E / 128);

  ParamsIE pi;
  pi.eidx = (const int*)d_in[0];
  pi.nl = (const float*)d_in[18];
  pi.b1 = (const float*)d_in[32]; pi.b2 = (const float*)d_in[34];
  pi.g  = (const float*)d_in[35]; pi.be = (const float*)d_in[36];
  pi.wt = wt; pi.msg = msg; pi.out = (float*)d_out;
  pi.E = E; pi.nt32 = E / 32;
  ie_kernel<<<256, 512, 131072, stream>>>(pi);
}

// Round 11
// 523.764 us; speedup vs baseline: 1.2200x; 1.1918x over previous
//
#include <hip/hip_runtime.h>

typedef __attribute__((ext_vector_type(4))) float fx4;
typedef __attribute__((ext_vector_type(8))) unsigned short u16x8;
typedef __attribute__((ext_vector_type(8))) __bf16 bf16x8;

static __device__ __forceinline__ unsigned short f2bf(float f) {
  unsigned int u = __builtin_bit_cast(unsigned int, f);
  u += 0x7fffu + ((u >> 16) & 1u);          // round-to-nearest-even
  return (unsigned short)(u >> 16);
}
static __device__ __forceinline__ fx4 mfma16(u16x8 a, u16x8 b, fx4 c) {
  return __builtin_amdgcn_mfma_f32_16x16x32_bf16(
      __builtin_bit_cast(bf16x8, a), __builtin_bit_cast(bf16x8, b), c, 0, 0, 0);
}

// XOR swizzles (16B-block granular). Weights are PRE-swizzled in ws by prep,
// so kernels copy them linearly into LDS and read with the same swizzle.
static __device__ __forceinline__ int swz128(int row, int col) {  // [.][128] bf16
  return row * 128 + (col ^ ((row & 7) << 3));
}
static __device__ __forceinline__ int swz32(int row, int col) {   // [.][32] bf16
  return row * 32 + (col ^ (((row >> 1) & 3) << 3));
}

// ---- ws layout (ushort units): weights bf16, [N][Kpad], pre-swizzled ----
#define WT_FE1 0        // [128][32]  (fe_W1, K=18 pad 32)
#define WT_FE2 4096     // [128][128] (fe_W2)
#define WT_EE1 20480    // [128][32]  (ee_W1, K=4 pad 32)
#define WT_EE2 24576    // [128][128] (ee_W2)
#define WT_A   40960    // [128][128] (ie_W1 rows 0..127   : sr_sum)
#define WT_B   57344    // [128][128] (ie_W1 rows 128..255 : node_sum)
#define WT_C   73728    // [128][128] (ie_W1 rows 256..383 : edge_latent)
#define WT_IE2 90112    // [128][128] (ie_W2)
#define WT_TOTAL 106496

__global__ void prep_weights(const float* __restrict__ feW1, const float* __restrict__ feW2,
                             const float* __restrict__ eeW1, const float* __restrict__ eeW2,
                             const float* __restrict__ ieW1, const float* __restrict__ ieW2,
                             unsigned short* __restrict__ wt) {
  int i = blockIdx.x * 256 + threadIdx.x;
  if (i >= WT_TOTAL) return;
  int base, n, k, kpad;
  float val;
  if (i < WT_FE2)      { base = WT_FE1; n = i >> 5; k = i & 31; kpad = 32;
                         val = (k < 18) ? feW1[k * 128 + n] : 0.f; }
  else if (i < WT_EE1) { base = WT_FE2; int j = i - WT_FE2; n = j >> 7; k = j & 127; kpad = 128;
                         val = feW2[k * 128 + n]; }
  else if (i < WT_EE2) { base = WT_EE1; int j = i - WT_EE1; n = j >> 5; k = j & 31; kpad = 32;
                         val = (k < 4) ? eeW1[k * 128 + n] : 0.f; }
  else if (i < WT_A)   { base = WT_EE2; int j = i - WT_EE2; n = j >> 7; k = j & 127; kpad = 128;
                         val = eeW2[k * 128 + n]; }
  else if (i < WT_B)   { base = WT_A;   int j = i - WT_A;   n = j >> 7; k = j & 127; kpad = 128;
                         val = ieW1[k * 128 + n]; }
  else if (i < WT_C)   { base = WT_B;   int j = i - WT_B;   n = j >> 7; k = j & 127; kpad = 128;
                         val = ieW1[(128 + k) * 128 + n]; }
  else if (i < WT_IE2) { base = WT_C;   int j = i - WT_C;   n = j >> 7; k = j & 127; kpad = 128;
                         val = ieW1[(256 + k) * 128 + n]; }
  else                 { base = WT_IE2; int j = i - WT_IE2; n = j >> 7; k = j & 127; kpad = 128;
                         val = ieW2[k * 128 + n]; }
  int dst = (kpad == 32) ? base + n * 32 + (k ^ (((n >> 1) & 3) << 3))
                         : base + n * 128 + (k ^ ((n & 7) << 3));
  wt[dst] = f2bf(val);
}

// 16-row GEMM, A from wave-local LDS arena, B from LDS (or global) weights,
// both swizzled.
template<int KPAD, int KT>
static __device__ __forceinline__ void gemm_lds(const unsigned short* As,
                                                const unsigned short* Ws,
                                                fx4* acc, int l16, int lgr) {
#pragma unroll
  for (int kk = 0; kk < KT; kk++) {
    const int k0 = kk * 32 + lgr * 8;
    u16x8 af = *(const u16x8*)(As + ((KPAD == 32) ? swz32(l16, k0) : swz128(l16, k0)));
#pragma unroll
    for (int nt = 0; nt < 8; nt++) {
      const int n = nt * 16 + l16;
      u16x8 bf = *(const u16x8*)(Ws + ((KPAD == 32) ? swz32(n, k0) : swz128(n, k0)));
      acc[nt] = mfma16(af, bf, acc[nt]);
    }
  }
}

// bias + ReLU -> bf16 store into wave-local [16][128] LDS slice.
static __device__ __forceinline__ void relu_store(fx4* acc, const float* __restrict__ bias,
                                                  unsigned short* dst, int l16, int lgr) {
#pragma unroll
  for (int nt = 0; nt < 8; nt++) {
    const int col = nt * 16 + l16;
    const float b = bias[col];
#pragma unroll
    for (int r = 0; r < 4; r++) {
      float v = acc[nt][r] + b;
      dst[swz128(lgr * 4 + r, col)] = f2bf(v > 0.f ? v : 0.f);
    }
  }
}

// bias add + per-row LayerNorm (normalize only; caller applies g/beta).
static __device__ __forceinline__ void ln_rows(fx4* acc, const float* __restrict__ bias, int l16) {
  float sum[4] = {0, 0, 0, 0}, sq[4] = {0, 0, 0, 0};
#pragma unroll
  for (int nt = 0; nt < 8; nt++) {
    const float b = bias[nt * 16 + l16];
#pragma unroll
    for (int r = 0; r < 4; r++) {
      float v = acc[nt][r] + b; acc[nt][r] = v;
      sum[r] += v; sq[r] += v * v;
    }
  }
#pragma unroll
  for (int r = 0; r < 4; r++) {
    float s_ = sum[r], q_ = sq[r];
#pragma unroll
    for (int m = 1; m < 16; m <<= 1) { s_ += __shfl_xor(s_, m, 64); q_ += __shfl_xor(q_, m, 64); }
    const float mu = s_ * (1.f / 128.f);
    const float rs = rsqrtf(q_ * (1.f / 128.f) - mu * mu + 1e-5f);
#pragma unroll
    for (int nt = 0; nt < 8; nt++) acc[nt][r] = (acc[nt][r] - mu) * rs;
  }
}

// ======================= fused fe+ee kernel (256 threads) =======================
// 256-thr blocks: measured VGPR cap 196 (512thr->128, 768->84, 1024->64) -- the
// only block size whose cap fits M=32 double-tiling without scratch spill.
// fe: M=32 = {16 senders rows 0..15, 16 receivers rows 16..31} of the SAME
// edges. Every B-fragment feeds 2 MFMAs; no serial side loop; latS replaced by
// in-register sum of the two LN'd halves.
// fe LDS: 40KB weights + 4 x (h1 8KB + feat 2KB) = 80KB -> 2 blocks/CU.
// ee LDS: 40KB weights + 4 x 2.5KB = 50KB.
struct ParamsFE {
  const float* basis[3];
  const float* sv[6]; const float* rv[6];
  const float* b1; const float* b2; const float* g; const float* be;
};
struct ParamsEE {
  const float* dx; const float* attr;
  const float* b1; const float* b2; const float* g; const float* be;
};

static __device__ __forceinline__ void fe_body(const ParamsFE& p, unsigned short* lds,
                                               const unsigned short* wt, unsigned short* msg,
                                               int bid, int nblocks, int ntiles) {
  const int tid = threadIdx.x;
  const int wave = tid >> 6, lane = tid & 63;
  const int l16 = lane & 15, lgr = lane >> 4;
#pragma unroll
  for (int i = tid * 8; i < 20480; i += 2048)
    *(u16x8*)(lds + i) = *(const u16x8*)(wt + WT_FE1 + i);
  const unsigned short* W1 = lds;
  const unsigned short* W2 = lds + 4096;
  unsigned short* h1 = lds + 20480 + wave * 5120;    // [32][128]
  unsigned short* feat = h1 + 4096;                  // [32][32]
  __syncthreads();
  // persistent zeros in feat cols 18..31, both halves
#pragma unroll
  for (int j = 0; j < 4; j++) {
    int c = 18 + lgr * 4 + j;
    if (c < 32) { feat[swz32(l16, c)] = 0; feat[swz32(16 + l16, c)] = 0; }
  }
  const fx4 z4 = {0.f, 0.f, 0.f, 0.f};

  for (int t = bid; t < ntiles; t += nblocks) {
    const int e0 = t * 64 + wave * 16;
    const size_t e = (size_t)(e0 + l16);
    float bx[3][3];
#pragma unroll
    for (int i = 0; i < 3; i++) {
      const float* bp = p.basis[i] + 3 * e;
      bx[i][0] = bp[0]; bx[i][1] = bp[1]; bx[i][2] = bp[2];
    }
    // features: rows l16 = sender, 16+l16 = receiver (compile-time k, rule #20)
#pragma unroll
    for (int k = 0; k < 6; k++) {
      if ((k & 3) == lgr) {
        const float* vs = p.sv[k] + 3 * e;
        const float* vr = p.rv[k] + 3 * e;
        const float s0 = vs[0], s1 = vs[1], s2 = vs[2];
        const float r0 = vr[0], r1 = vr[1], r2 = vr[2];
        const float sgn = (k != 3 && k != 5) ? -1.f : 1.f;  // receiver signs
#pragma unroll
        for (int i = 0; i < 3; i++) {
          feat[swz32(l16, k * 3 + i)] =
              f2bf(bx[i][0] * s0 + bx[i][1] * s1 + bx[i][2] * s2);
          feat[swz32(16 + l16, k * 3 + i)] =
              f2bf((bx[i][0] * r0 + bx[i][1] * r1 + bx[i][2] * r2) * sgn);
        }
      }
    }
    fx4 accA[8], accB[8];
#pragma unroll
    for (int b = 0; b < 8; b++) { accA[b] = z4; accB[b] = z4; }
    // layer1 K=32, B shared by both halves
    {
      const int k0 = lgr * 8;
      u16x8 afA = *(const u16x8*)(feat + swz32(l16, k0));
      u16x8 afB = *(const u16x8*)(feat + swz32(16 + l16, k0));
#pragma unroll
      for (int nt = 0; nt < 8; nt++) {
        u16x8 bf = *(const u16x8*)(W1 + swz32(nt * 16 + l16, k0));
        accA[nt] = mfma16(afA, bf, accA[nt]);
        accB[nt] = mfma16(afB, bf, accB[nt]);
      }
    }
    relu_store(accA, p.b1, h1, l16, lgr);
    relu_store(accB, p.b1, h1 + 2048, l16, lgr);
#pragma unroll
    for (int b = 0; b < 8; b++) { accA[b] = z4; accB[b] = z4; }
    // layer2 K=128, B shared
#pragma unroll
    for (int c = 0; c < 4; c++) {
      const int k0 = c * 32 + lgr * 8;
      u16x8 afA = *(const u16x8*)(h1 + swz128(l16, k0));
      u16x8 afB = *(const u16x8*)(h1 + 2048 + swz128(l16, k0));
#pragma unroll
      for (int nt = 0; nt < 8; nt++) {
        u16x8 bf = *(const u16x8*)(W2 + swz128(nt * 16 + l16, k0));
        accA[nt] = mfma16(afA, bf, accA[nt]);
        accB[nt] = mfma16(afB, bf, accB[nt]);
      }
    }
    ln_rows(accA, p.b2, l16);
    ln_rows(accB, p.b2, l16);
    // sr_sum = (lnA*g+be) + (lnB*g+be), straight to msg cols 0..127
#pragma unroll
    for (int nt = 0; nt < 8; nt++) {
      const int col = nt * 16 + l16;
      const float gg = p.g[col], bb = p.be[col];
#pragma unroll
      for (int r = 0; r < 4; r++)
        msg[(size_t)(e0 + lgr * 4 + r) * 256 + col] =
            f2bf(accA[nt][r] * gg + bb + accB[nt][r] * gg + bb);
    }
  }
}

static __device__ __forceinline__ void ee_body(const ParamsEE& p, unsigned short* lds,
                                               const unsigned short* wt, unsigned short* msg,
                                               int bid, int nblocks, int ntiles) {
  const int tid = threadIdx.x;
  const int wave = tid >> 6, lane = tid & 63;
  const int l16 = lane & 15, lgr = lane >> 4;
#pragma unroll
  for (int i = tid * 8; i < 20480; i += 2048)
    *(u16x8*)(lds + i) = *(const u16x8*)(wt + WT_EE1 + i);
  const unsigned short* W1 = lds;
  const unsigned short* W2 = lds + 4096;
  unsigned short* h1 = lds + 20480 + wave * 2560;
  unsigned short* feat = h1 + 2048;
  __syncthreads();
  // persistent zeros cols 4..31
#pragma unroll
  for (int j = 0; j < 7; j++) feat[swz32(l16, 4 + lgr * 7 + j)] = 0;
  const fx4 z4 = {0.f, 0.f, 0.f, 0.f};

  for (int t = bid; t < ntiles; t += nblocks) {
    const int e0 = t * 64 + wave * 16;
    const size_t e = (size_t)(e0 + l16);
    if (lgr == 0) {
      float d0 = p.dx[3 * e], d1 = p.dx[3 * e + 1], d2 = p.dx[3 * e + 2];
      feat[swz32(l16, 0)] = f2bf(sqrtf(d0 * d0 + d1 * d1 + d2 * d2));
    } else {
      feat[swz32(l16, lgr)] = f2bf(p.attr[3 * e + (lgr - 1)]);
    }
    fx4 acc[8];
#pragma unroll
    for (int b = 0; b < 8; b++) acc[b] = z4;
    gemm_lds<32, 1>(feat, W1, acc, l16, lgr);
    relu_store(acc, p.b1, h1, l16, lgr);
#pragma unroll
    for (int b = 0; b < 8; b++) acc[b] = z4;
    gemm_lds<128, 4>(h1, W2, acc, l16, lgr);
    ln_rows(acc, p.b2, l16);
#pragma unroll
    for (int nt = 0; nt < 8; nt++) {
      const int col = nt * 16 + l16;
      const float gg = p.g[col], bb = p.be[col];
#pragma unroll
      for (int r = 0; r < 4; r++)
        msg[(size_t)(e0 + lgr * 4 + r) * 256 + 128 + col] =
            f2bf(acc[nt][r] * gg + bb);
    }
  }
}

__global__ __launch_bounds__(256) void feee_kernel(ParamsFE pf, ParamsEE pe,
                                                   const unsigned short* wt,
                                                   unsigned short* msg,
                                                   int nfe, int ntiles) {
  extern __shared__ unsigned short lds[];  // 40960 ushorts (80KB)
  if ((int)blockIdx.x < nfe)
    fe_body(pf, lds, wt, msg, blockIdx.x, nfe, ntiles);
  else
    ee_body(pe, lds, wt, msg, blockIdx.x - nfe, gridDim.x - nfe, ntiles);
}

// ============ ie kernel (fused layer1 + layer2 + LN -> out f32) ============
// EXACT R7 config (proven 301us, VGPR 128 = the 512-thr cap, no spill).
// 512 threads = 8 waves. Dyn LDS 128KB: WA|WB|WC 96KB + 8 x 4KB arenas.
// 1 block/CU. W2 (32KB) read from GLOBAL per-fragment (L1-resident).
// NEVER 768/1024 threads (VGPR caps 84/64 spill the accumulators, R6/R8);
// M=32 at 512thr also spills (R10: needs ~180 > cap 128).
struct ParamsIE {
  const int* eidx;
  const float* nl;
  const float* b1; const float* b2; const float* g; const float* be;
  const unsigned short* wt;
  const unsigned short* msg;  // aliases out (rows consumed before overwrite)
  float* out;
  int E; int ntiles;
};

__global__ __launch_bounds__(512) void ie_kernel(ParamsIE p) {
  extern __shared__ unsigned short dyn[];  // 49152 weights + 8*2048 arenas
  const int tid = threadIdx.x;
  const int wave = tid >> 6, lane = tid & 63;
  const int l16 = lane & 15, lgr = lane >> 4;
#pragma unroll
  for (int i = tid * 8; i < 49152; i += 4096)
    *(u16x8*)(dyn + i) = *(const u16x8*)(p.wt + WT_A + i);
  const unsigned short* WA = dyn;
  const unsigned short* WB = dyn + 16384;
  const unsigned short* WC = dyn + 32768;
  unsigned short* h1 = dyn + 49152 + wave * 2048;
  __syncthreads();
  const fx4 z4 = {0.f, 0.f, 0.f, 0.f};

  for (int t = blockIdx.x; t < p.ntiles; t += gridDim.x) {
    const int e0 = t * 128 + wave * 16;
    const size_t e = (size_t)(e0 + l16);
    const int sidx = p.eidx[e];
    const int ridx = p.eidx[(size_t)p.E + e];
    const unsigned short* mrow = p.msg + e * 256;
    const float* ns = p.nl + (size_t)sidx * 128;
    const float* nr = p.nl + (size_t)ridx * 128;
    fx4 acc[8];
#pragma unroll
    for (int b = 0; b < 8; b++) acc[b] = z4;
    // node chunks first (longest-latency gathers issue early)
#pragma unroll
    for (int c = 0; c < 4; c++) {
      const int k0 = c * 32 + lgr * 8;
      fx4 a0 = *(const fx4*)(ns + k0), a1 = *(const fx4*)(ns + k0 + 4);
      fx4 b0 = *(const fx4*)(nr + k0), b1 = *(const fx4*)(nr + k0 + 4);
      u16x8 af;
#pragma unroll
      for (int j = 0; j < 4; j++) { af[j] = f2bf(a0[j] + b0[j]); af[4 + j] = f2bf(a1[j] + b1[j]); }
#pragma unroll
      for (int nt = 0; nt < 8; nt++) {
        u16x8 bf = *(const u16x8*)(WB + swz128(nt * 16 + l16, k0));
        acc[nt] = mfma16(af, bf, acc[nt]);
      }
    }
    // sr chunks (msg cols 0..127, linear layout)
#pragma unroll
    for (int c = 0; c < 4; c++) {
      const int k0 = c * 32 + lgr * 8;
      u16x8 af = *(const u16x8*)(mrow + k0);
#pragma unroll
      for (int nt = 0; nt < 8; nt++) {
        u16x8 bf = *(const u16x8*)(WA + swz128(nt * 16 + l16, k0));
        acc[nt] = mfma16(af, bf, acc[nt]);
      }
    }
    // el chunks (msg cols 128..255)
#pragma unroll
    for (int c = 0; c < 4; c++) {
      const int k0 = c * 32 + lgr * 8;
      u16x8 af = *(const u16x8*)(mrow + 128 + k0);
#pragma unroll
      for (int nt = 0; nt < 8; nt++) {
        u16x8 bf = *(const u16x8*)(WC + swz128(nt * 16 + l16, k0));
        acc[nt] = mfma16(af, bf, acc[nt]);
      }
    }
    // ReLU -> per-wave LDS arena
    relu_store(acc, p.b1, h1, l16, lgr);
    // layer 2: A from arena (LDS), B from global W2 (L1-resident 32KB)
#pragma unroll
    for (int b = 0; b < 8; b++) acc[b] = z4;
    gemm_lds<128, 4>(h1, p.wt + WT_IE2, acc, l16, lgr);
    ln_rows(acc, p.b2, l16);
#pragma unroll
    for (int nt = 0; nt < 8; nt++) {
      const int col = nt * 16 + l16;
      const float gg = p.g[col], bb = p.be[col];
#pragma unroll
      for (int r = 0; r < 4; r++)
        p.out[(size_t)(e0 + lgr * 4 + r) * 128 + col] = acc[nt][r] * gg + bb;
    }
  }
}

extern "C" void kernel_launch(void* const* d_in, const int* in_sizes, int n_in,
                              void* d_out, int out_size, void* d_ws, size_t ws_size,
                              hipStream_t stream) {
  (void)n_in; (void)out_size;
  const int E = in_sizes[1] / 3;  // edge_dx_ is [E,3]
  unsigned short* wt = reinterpret_cast<unsigned short*>(d_ws);
  if (ws_size < (size_t)WT_TOTAL * sizeof(unsigned short)) return;

  prep_weights<<<(WT_TOTAL + 255) / 256, 256, 0, stream>>>(
      (const float*)d_in[19], (const float*)d_in[21],
      (const float*)d_in[25], (const float*)d_in[27],
      (const float*)d_in[31], (const float*)d_in[33], wt);

  unsigned short* msg = (unsigned short*)d_out;  // [E][256] bf16 staging inside d_out

  hipFuncSetAttribute((const void*)feee_kernel,
                      hipFuncAttributeMaxDynamicSharedMemorySize, 81920);
  hipFuncSetAttribute((const void*)ie_kernel,
                      hipFuncAttributeMaxDynamicSharedMemorySize, 131072);

  ParamsFE pf;
  for (int i = 0; i < 3; i++) pf.basis[i] = (const float*)d_in[3 + i];
  for (int k = 0; k < 6; k++) { pf.sv[k] = (const float*)d_in[6 + k]; pf.rv[k] = (const float*)d_in[12 + k]; }
  pf.b1 = (const float*)d_in[20]; pf.b2 = (const float*)d_in[22];
  pf.g  = (const float*)d_in[23]; pf.be = (const float*)d_in[24];

  ParamsEE pe;
  pe.dx = (const float*)d_in[1]; pe.attr = (const float*)d_in[2];
  pe.b1 = (const float*)d_in[26]; pe.b2 = (const float*)d_in[28];
  pe.g  = (const float*)d_in[29]; pe.be = (const float*)d_in[30];

  // fe: E/64 tiles over 1024 blocks; ee: E/64 tiles over 512 blocks (~2:1 work)
  feee_kernel<<<1536, 256, 81920, stream>>>(pf, pe, wt, msg, 1024, E / 64);

  ParamsIE pi;
  pi.eidx = (const int*)d_in[0];
  pi.nl = (const float*)d_in[18];
  pi.b1 = (const float*)d_in[32]; pi.b2 = (const float*)d_in[34];
  pi.g  = (const float*)d_in[35]; pi.be = (const float*)d_in[36];
  pi.wt = wt; pi.msg = msg; pi.out = (float*)d_out;
  pi.E = E; pi.ntiles = E / 128;
  ie_kernel<<<256, 512, 131072, stream>>>(pi);
}